// Round 1
// baseline (10.107 us; speedup 1.0000x reference)
//
#include <hip/hip_runtime.h>

// AtIndexPooler: out[b, i*H + h] = indices[b,i] >= 0
//                  ? hidden_state[b, clip(indices[b,i], 0, S-1), h]
//                  : missing_embeddings[i, h]
// Shapes: hidden_state (512, 512, 1024) f32, missing_embeddings (2, 1024) f32,
//         indices (512, 2) int32, out (512, 2048) f32.

#define BATCH    512
#define SEQ_LEN  512
#define HIDDEN   1024
#define NUM_IDX  2

// One block per output row (batch * NUM_IDX = 1024 rows).
// 256 threads x float4 = 1024 floats per row, fully coalesced 16B/lane.
__global__ void __launch_bounds__(256)
at_index_pooler_kernel(const float* __restrict__ hidden,
                       const float* __restrict__ missing,
                       const int* __restrict__ indices,
                       float* __restrict__ out) {
    const int row = blockIdx.x;        // 0 .. BATCH*NUM_IDX-1
    const int b   = row >> 1;          // NUM_IDX == 2
    const int i   = row & 1;
    const int t   = threadIdx.x;       // 0..255, each handles one float4

    const int ind   = indices[b * NUM_IDX + i];
    const bool valid = (ind >= 0);
    int idx = ind;                     // OFFSET == 0
    idx = idx < 0 ? 0 : (idx > SEQ_LEN - 1 ? SEQ_LEN - 1 : idx);

    const float4* src;
    if (valid) {
        src = reinterpret_cast<const float4*>(
            hidden + ((size_t)b * SEQ_LEN + (size_t)idx) * HIDDEN);
    } else {
        src = reinterpret_cast<const float4*>(missing + (size_t)i * HIDDEN);
    }
    float4* dst = reinterpret_cast<float4*>(out + (size_t)row * HIDDEN);

    dst[t] = src[t];
}

extern "C" void kernel_launch(void* const* d_in, const int* in_sizes, int n_in,
                              void* d_out, int out_size, void* d_ws, size_t ws_size,
                              hipStream_t stream) {
    const float* hidden  = (const float*)d_in[0];
    const float* missing = (const float*)d_in[1];
    const int*   indices = (const int*)d_in[2];
    float* out = (float*)d_out;

    dim3 grid(BATCH * NUM_IDX);
    dim3 block(256);
    at_index_pooler_kernel<<<grid, block, 0, stream>>>(hidden, missing, indices, out);
}

// Round 2
// 10.107 us; speedup vs baseline: 1.0000x; 1.0000x over previous
//
#include <hip/hip_runtime.h>

// AtIndexPooler: out[b, i*H + h] = indices[b,i] >= 0
//                  ? hidden_state[b, clip(indices[b,i], 0, S-1), h]
//                  : missing_embeddings[i, h]
// Shapes: hidden_state (512, 512, 1024) f32, missing_embeddings (2, 1024) f32,
//         indices (512, 2) int32, out (512, 2048) f32.
//
// R2 variant: one block per batch (512 blocks, 256 threads). Each block loads
// both indices once and copies both 4 KB rows (2x float4 per thread).
// Purpose: test launch-floor hypothesis (predict: dur unchanged ~10 us).

#define BATCH    512
#define SEQ_LEN  512
#define HIDDEN   1024
#define NUM_IDX  2

__global__ void __launch_bounds__(256)
at_index_pooler_kernel(const float* __restrict__ hidden,
                       const float* __restrict__ missing,
                       const int* __restrict__ indices,
                       float* __restrict__ out) {
    const int b = blockIdx.x;          // 0 .. BATCH-1
    const int t = threadIdx.x;         // 0..255

    // Both indices for this batch in one 8B load (uniform across block ->
    // compiler emits scalar load).
    const int2 ip = *reinterpret_cast<const int2*>(indices + b * NUM_IDX);

    const float* base_b = hidden + (size_t)b * SEQ_LEN * HIDDEN;

    #pragma unroll
    for (int i = 0; i < NUM_IDX; ++i) {
        const int ind = (i == 0) ? ip.x : ip.y;
        int idx = ind < 0 ? 0 : (ind > SEQ_LEN - 1 ? SEQ_LEN - 1 : ind);

        const float4* src = (ind >= 0)
            ? reinterpret_cast<const float4*>(base_b + (size_t)idx * HIDDEN)
            : reinterpret_cast<const float4*>(missing + (size_t)i * HIDDEN);

        float4* dst = reinterpret_cast<float4*>(
            out + ((size_t)b * NUM_IDX + i) * HIDDEN);

        dst[t] = src[t];
    }
}

extern "C" void kernel_launch(void* const* d_in, const int* in_sizes, int n_in,
                              void* d_out, int out_size, void* d_ws, size_t ws_size,
                              hipStream_t stream) {
    const float* hidden  = (const float*)d_in[0];
    const float* missing = (const float*)d_in[1];
    const int*   indices = (const int*)d_in[2];
    float* out = (float*)d_out;

    dim3 grid(BATCH);
    dim3 block(256);
    at_index_pooler_kernel<<<grid, block, 0, stream>>>(hidden, missing, indices, out);
}